// Round 9
// baseline (284.516 us; speedup 1.0000x reference)
//
#include <hip/hip_runtime.h>
#include <stdint.h>

typedef short s16x8 __attribute__((ext_vector_type(8)));
typedef float f32x4 __attribute__((ext_vector_type(4)));

#define IN_F   256
#define OUT_F  256
#define BATCH  16384

__device__ __forceinline__ unsigned short f2bf(float f) {
    unsigned u = __float_as_uint(f);
    u += 0x7FFFu + ((u >> 16) & 1u);   // RNE
    return (unsigned short)(u >> 16);
}

// ---------------- kernel 1: per-column min/max partials ----------------
__global__ void minmax_partial(const float* __restrict__ x,
                               float* __restrict__ pmin, float* __restrict__ pmax) {
    const int t = threadIdx.x;           // column
    const int b = blockIdx.x;            // row chunk of 128
    float mn = 3.4e38f, mx = -3.4e38f;
    for (int r = 0; r < 128; ++r) {
        float v = x[(size_t)(b * 128 + r) * IN_F + t];
        mn = fminf(mn, v);
        mx = fmaxf(mx, v);
    }
    pmin[b * IN_F + t] = mn;
    pmax[b * IN_F + t] = mx;
}

// ---------------- kernel 2: finalize min + f32 denom + CR reciprocal ----------------
__global__ void minmax_final(const float* __restrict__ pmin, const float* __restrict__ pmax,
                             float* __restrict__ xmin, float* __restrict__ rden) {
    const int t = threadIdx.x;
    float mn = pmin[t], mx = pmax[t];
    for (int j = 1; j < 128; ++j) {
        mn = fminf(mn, pmin[j * IN_F + t]);
        mx = fmaxf(mx, pmax[j * IN_F + t]);
    }
    xmin[t] = mn;
    float den = mx - mn + 1e-8f;         // f32, eps absorbed (textbook)
    rden[t] = 1.0f / den;                // correctly-rounded f32 reciprocal
}

// ---------------- kernel 3: Haar fold V[o][i][32] in f32 + bw->bf16 ----------------
__global__ void vbuild(const float* __restrict__ sw, const float* __restrict__ sc,
                       const float* __restrict__ bw,
                       float* __restrict__ Vf, unsigned short* __restrict__ bwb) {
    const int o = blockIdx.x, i = threadIdx.x;
    const float* w = sw + ((size_t)o * IN_F + i) * 31;
    const float s = sc[o * IN_F + i];
#pragma unroll
    for (int j = 0; j < 32; ++j) {
        float acc = ((j >> 4) & 1) ? -w[0] : w[0];
        float w1 = w[1 + (j >> 4)];  acc += ((j >> 3) & 1) ? -w1 : w1;
        float w2 = w[3 + (j >> 3)];  acc += ((j >> 2) & 1) ? -w2 : w2;
        float w3 = w[7 + (j >> 2)];  acc += ((j >> 1) & 1) ? -w3 : w3;
        float w4 = w[15 + (j >> 1)]; acc += (j & 1) ? -w4 : w4;
        Vf[((size_t)o * IN_F + i) * 32 + j] = acc * s;
    }
    bwb[o * IN_F + i] = f2bf(bw[o * IN_F + i]);
}

// ---------------- kernel 4: leaf via RECIPROCAL-MULTIPLY normalization ----------------
// Probe: ref xn = fl32( (x - xmin) * fl32(1/denom) )  — fast-div lowering.
// Differs from CR division by up to ~1 ulp at interior points -> the invariant
// flip set S_A. Boundary behavior unchanged: num==0 -> xn=0 -> leaf 0;
// x==xmax -> num*r: range*fl(1/range') rounds to 1.0f -> leaf 32 -> zero.
__global__ void leafk(const float* __restrict__ x, const float* __restrict__ xmin,
                      const float* __restrict__ rden, unsigned char* __restrict__ leaf) {
    const int b = blockIdx.x, i = threadIdx.x;
    float num = x[(size_t)b * IN_F + i] - xmin[i];
    float xn  = num * rden[i];                   // rcp-mult (NOT CR division)
    int l = (int)(xn * 32.0f);                   // exact pow2 scale; trunc==floor
    leaf[(size_t)b * IN_F + i] = (l >= 0 && l < 32) ? (unsigned char)l : (unsigned char)255;
}

// ---------------- kernel 5: base_out = relu(x) @ bw^T via MFMA ----------------
__global__ __launch_bounds__(256, 1) void relu_gemm(
    const float* __restrict__ x, const unsigned short* __restrict__ bwb,
    float* __restrict__ out) {
    __shared__ unsigned short As[128 * 72];
    __shared__ unsigned short Bs[128 * 72];
    const int tid = threadIdx.x, lane = tid & 63, wid = tid >> 6;
    const int mtile = blockIdx.x, ntile = blockIdx.y;
    const int wm = wid >> 1, wn = wid & 1;
    f32x4 acc[4][4] = {};

    for (int kb = 0; kb < 4; ++kb) {
#pragma unroll
        for (int q = 0; q < 4; ++q) {
            int slot = tid + q * 256;
            int n = slot >> 3, c = slot & 7;
            const unsigned short* src = bwb + (size_t)(ntile * 128 + n) * IN_F + kb * 64 + c * 8;
            *(s16x8*)&Bs[n * 72 + c * 8] = *(const s16x8*)src;
        }
        {
            int am = tid >> 1, ag = tid & 1;
            const float* xr = x + (size_t)(mtile * 128 + am) * IN_F + kb * 64 + ag * 32;
#pragma unroll
            for (int q = 0; q < 4; ++q) {
                union { s16x8 v; unsigned short u[8]; } t8;
#pragma unroll
                for (int j = 0; j < 8; ++j) t8.u[j] = f2bf(fmaxf(xr[q * 8 + j], 0.0f));
                *(s16x8*)&As[am * 72 + (ag * 4 + q) * 8] = t8.v;
            }
        }
        __syncthreads();
#pragma unroll
        for (int ks = 0; ks < 2; ++ks) {
            const int rr = lane & 15, kq = lane >> 4, c = ks * 4 + kq;
            s16x8 af[4], bfr[4];
#pragma unroll
            for (int mt = 0; mt < 4; ++mt)
                af[mt] = *(const s16x8*)&As[(wm * 64 + mt * 16 + rr) * 72 + c * 8];
#pragma unroll
            for (int nt = 0; nt < 4; ++nt)
                bfr[nt] = *(const s16x8*)&Bs[(wn * 64 + nt * 16 + rr) * 72 + c * 8];
#pragma unroll
            for (int mt = 0; mt < 4; ++mt)
#pragma unroll
                for (int nt = 0; nt < 4; ++nt)
                    acc[mt][nt] = __builtin_amdgcn_mfma_f32_16x16x32_bf16(
                        af[mt], bfr[nt], acc[mt][nt], 0, 0, 0);
        }
        __syncthreads();
    }
    const int rr = lane & 15, rq = lane >> 4;
#pragma unroll
    for (int mt = 0; mt < 4; ++mt)
#pragma unroll
        for (int nt = 0; nt < 4; ++nt)
#pragma unroll
            for (int v = 0; v < 4; ++v) {
                int row = mtile * 128 + wm * 64 + mt * 16 + rq * 4 + v;
                int col = ntile * 128 + wn * 64 + nt * 16 + rr;
                out[(size_t)row * OUT_F + col] = acc[mt][nt][v];
            }
}

// ---------------- kernel 6: wavelet gather: out[b,o] += sum_i V[o,i,leaf(b,i)] ----
__global__ __launch_bounds__(256) void gatherk(
    const float* __restrict__ Vf, const unsigned char* __restrict__ leaf,
    float* __restrict__ out) {
    const int o = blockIdx.x, bc = blockIdx.y;
    __shared__ float Vs[8192];             // V[o][i=0..255][j=0..31], 32 KB
    for (int k = threadIdx.x; k < 8192; k += 256)
        Vs[k] = Vf[(size_t)o * 8192 + k];
    __syncthreads();
#pragma unroll 1
    for (int r = 0; r < 16; ++r) {
        const int b = bc * 4096 + r * 256 + threadIdx.x;
        const uint4* lp = (const uint4*)(leaf + (size_t)b * IN_F);
        float acc = 0.0f;
#pragma unroll
        for (int ic = 0; ic < 16; ++ic) {
            uint4 L = lp[ic];
            unsigned w[4] = {L.x, L.y, L.z, L.w};
#pragma unroll
            for (int q = 0; q < 4; ++q)
#pragma unroll
                for (int byi = 0; byi < 4; ++byi) {
                    unsigned l = (w[q] >> (8 * byi)) & 255u;
                    int i = ic * 16 + q * 4 + byi;
                    float v = Vs[i * 32 + (l & 31)];   // safe index
                    acc += (l < 32u) ? v : 0.0f;       // l==255 -> zero bases
                }
        }
        out[(size_t)b * OUT_F + o] += acc;
    }
}

// ---------------- host ----------------
extern "C" void kernel_launch(void* const* d_in, const int* in_sizes, int n_in,
                              void* d_out, int out_size, void* d_ws, size_t ws_size,
                              hipStream_t stream) {
    (void)in_sizes; (void)n_in; (void)out_size; (void)ws_size;
    const float* x  = (const float*)d_in[0];   // [16384,256]
    const float* bw = (const float*)d_in[1];   // [256,256]
    const float* sw = (const float*)d_in[2];   // [256,256,31]
    const float* sc = (const float*)d_in[3];   // [256,256]
    float* out = (float*)d_out;

    char* ws = (char*)d_ws;
    float*          Vf   = (float*)(ws);                       // 8,388,608
    unsigned short* bwb  = (unsigned short*)(ws + 8388608);    // 131,072
    unsigned char*  leaf = (unsigned char*)(ws + 8519680);     // 4,194,304
    float* pmin  = (float*)(ws + 12713984);                    // 131,072
    float* pmax  = (float*)(ws + 12845056);                    // 131,072
    float* xmin  = (float*)(ws + 12976128);                    // 1,024
    float* rden  = (float*)(ws + 12977152);                    // 1,024

    minmax_partial<<<128, 256, 0, stream>>>(x, pmin, pmax);
    minmax_final<<<1, 256, 0, stream>>>(pmin, pmax, xmin, rden);
    vbuild<<<256, 256, 0, stream>>>(sw, sc, bw, Vf, bwb);
    leafk<<<16384, 256, 0, stream>>>(x, xmin, rden, leaf);
    relu_gemm<<<dim3(128, 2), 256, 0, stream>>>(x, bwb, out);
    gatherk<<<dim3(256, 4), 256, 0, stream>>>(Vf, leaf, out);
}

// Round 10
// 279.085 us; speedup vs baseline: 1.0195x; 1.0195x over previous
//
#include <hip/hip_runtime.h>
#include <stdint.h>

typedef short s16x8 __attribute__((ext_vector_type(8)));
typedef float f32x4 __attribute__((ext_vector_type(4)));

#define IN_F   256
#define OUT_F  256
#define BATCH  16384
#define NB     31
#define KONE   8192          // 256 groups * 32 one-hot slots
#define KTOT   8448          // + 256 relu tail

typedef const __attribute__((address_space(1))) void* as1cvp;
typedef __attribute__((address_space(3))) void* as3vp;

__device__ __forceinline__ unsigned short f2bf(float f) {
    unsigned u = __float_as_uint(f);
    u += 0x7FFFu + ((u >> 16) & 1u);   // RNE
    return (unsigned short)(u >> 16);
}

// ---------------- kernel 1: per-column min/max partials ----------------
__global__ void minmax_partial(const float* __restrict__ x,
                               float* __restrict__ pmin, float* __restrict__ pmax) {
    const int t = threadIdx.x;           // column
    const int b = blockIdx.x;            // row chunk of 128
    float mn = 3.4e38f, mx = -3.4e38f;
    for (int r = 0; r < 128; ++r) {
        float v = x[(size_t)(b * 128 + r) * IN_F + t];
        mn = fminf(mn, v);
        mx = fmaxf(mx, v);
    }
    pmin[b * IN_F + t] = mn;
    pmax[b * IN_F + t] = mx;
}

// ---------------- kernel 2: finalize min + CR reciprocal of f32 denom ----------------
// Verified reference chain (R9 PASS): xn = (x - xmin) * fl32(1/((xmax-xmin)+1e-8f))
__global__ void minmax_final(const float* __restrict__ pmin, const float* __restrict__ pmax,
                             float* __restrict__ xmin, float* __restrict__ rden) {
    const int t = threadIdx.x;
    float mn = pmin[t], mx = pmax[t];
    for (int j = 1; j < 128; ++j) {
        mn = fminf(mn, pmin[j * IN_F + t]);
        mx = fmaxf(mx, pmax[j * IN_F + t]);
    }
    xmin[t] = mn;
    rden[t] = 1.0f / (mx - mn + 1e-8f);
}

// ---------------- kernel 3: build W = [Haar-synthesized V | bw] in bf16 ----------------
// Wb layout: [n=OUT][k=KTOT] row-major (row stride KTOT*2B = 16896B, 16B aligned)
__global__ void build_wb(const float* __restrict__ bw, const float* __restrict__ sw,
                         const float* __restrict__ sc, unsigned short* __restrict__ Wb) {
    const int o = blockIdx.x;
    const int t = threadIdx.x;
    for (int k = t; k < KTOT; k += 256) {
        float val;
        if (k < KONE) {
            int i = k >> 5, j = k & 31;          // leaf j of feature i
            float s = sc[o * IN_F + i];
            float acc = 0.f;
#pragma unroll
            for (int l = 0; l < 5; ++l) {
                int kk = (1 << l) - 1 + (j >> (5 - l));
                float w = sw[((size_t)(o * IN_F + i)) * NB + kk];
                acc += (((j >> (4 - l)) & 1) ? -w : w);
            }
            val = acc * s;
        } else {
            val = bw[o * IN_F + (k - KONE)];
        }
        Wb[(size_t)o * KTOT + k] = f2bf(val);
    }
}

// ---------------- kernel 4: fused one-hot GEMM (machinery proven R1≡R4) ----------
// C[16384,256] = A[16384,8448] * Wb[256,8448]^T, A generated on the fly.
// 128x128 tile, BK=64, 4 waves in 2x2 (wave tile 64x64), mfma 16x16x32 bf16.
__global__ __launch_bounds__(256, 1) void gemm_kan(
    const float* __restrict__ x,
    const unsigned short* __restrict__ Wb,
    const float* __restrict__ xminp,
    const float* __restrict__ rdenp,
    float* __restrict__ out)
{
    __shared__ unsigned short Ash[128 * 64];   // 16KB, XOR-swizzled chunks
    __shared__ unsigned short Bsh[128 * 64];   // 16KB, XOR-swizzled chunks
    __shared__ float xsh[128 * 65];            // x slab, +1 dword pad
    __shared__ float xminsh[IN_F];
    __shared__ float rdensh[IN_F];

    const int tid   = threadIdx.x;
    const int lane  = tid & 63;
    const int wid   = tid >> 6;
    const int mtile = blockIdx.x;
    const int ntile = blockIdx.y;
    const int wm    = wid >> 1;
    const int wn    = wid & 1;

    xminsh[tid] = xminp[tid];
    rdensh[tid] = rdenp[tid];
    {   // zero A tile once; one-hot writes keep it clean thereafter
        uint4 z; z.x = z.y = z.z = z.w = 0u;
        uint4* a4 = (uint4*)Ash;
#pragma unroll
        for (int r = 0; r < 4; ++r) a4[tid + r * 256] = z;
    }
    __syncthreads();

    f32x4 acc[4][4] = {};

    const int am = tid >> 1;   // row 0..127 this thread stages
    const int ag = tid & 1;    // which 32-slot group within BK=64
    int prevSlot = -1;

    for (int kb = 0; kb < 132; ++kb) {
        // ---- issue B staging (16B/lane direct-to-LDS), swizzle via source addr ----
#pragma unroll
        for (int q = 0; q < 4; ++q) {
            int n = ((wid * 4 + q) << 3) + (lane >> 3);   // 0..127
            const unsigned short* src = Wb + (size_t)(ntile * 128 + n) * KTOT
                                        + kb * 64 + (((lane & 7) ^ (n & 7)) << 3);
            __builtin_amdgcn_global_load_lds(
                (as1cvp)(uintptr_t)src,
                (as3vp)(uint32_t)(uintptr_t)(Bsh + (wid * 4 + q) * 512),
                16, 0, 0);
        }

        if (kb < 128) {
            if ((kb & 31) == 0) {   // stage next 64 features of x
                __syncthreads();
                const int ibase = (kb >> 5) * 64;
#pragma unroll
                for (int r = 0; r < 32; ++r) {
                    int idx = r * 256 + tid;
                    int row = idx >> 6, ic = idx & 63;
                    xsh[row * 65 + ic] = x[(size_t)(mtile * 128 + row) * IN_F + ibase + ic];
                }
                __syncthreads();
            }
            // ---- one-hot A generation, rcp-mult chain (verified R9) ----
            const int i  = kb * 2 + ag;
            const int il = (kb & 31) * 2 + ag;
            float xv  = xsh[am * 65 + il];
            float num = xv - xminsh[i];
            float xn  = num * rdensh[i];          // rcp-mult, NOT division
            int leaf  = (int)(xn * 32.0f);        // exact pow2 scale; trunc==floor
            if (prevSlot >= 0) Ash[prevSlot] = 0;
            if (leaf >= 0 && leaf < 32) {
                int c = (ag << 2) + (leaf >> 3);
                int slot = (am << 6) + ((c ^ (am & 7)) << 3) + (leaf & 7);
                Ash[slot] = 0x3F80;               // bf16 1.0
                prevSlot = slot;
            } else {
                prevSlot = -1;                    // xn out of [0,1) -> zero bases
            }
        } else {
            // ---- dense relu(x) tail (4 iters), overwrites whole half-rows ----
            __syncthreads();
            const int ibase = (kb - 128) * 64;
#pragma unroll
            for (int r = 0; r < 32; ++r) {
                int idx = r * 256 + tid;
                int row = idx >> 6, ic = idx & 63;
                xsh[row * 65 + ic] = x[(size_t)(mtile * 128 + row) * IN_F + ibase + ic];
            }
            __syncthreads();
#pragma unroll
            for (int q = 0; q < 4; ++q) {
                int c = (ag << 2) + q;
                union { s16x8 v; unsigned short u[8]; } tmp;
#pragma unroll
                for (int j = 0; j < 8; ++j) {
                    float xv = xsh[am * 65 + (ag * 32 + q * 8 + j)];
                    tmp.u[j] = f2bf(fmaxf(xv, 0.0f));
                }
                *(s16x8*)&Ash[(am << 6) + ((c ^ (am & 7)) << 3)] = tmp.v;
            }
        }

        __syncthreads();   // drains glds (vmcnt) + LDS writes

        // ---- MFMA phase: two 32-wide K slices ----
#pragma unroll
        for (int ks = 0; ks < 2; ++ks) {
            const int rr = lane & 15;
            const int kq = lane >> 4;
            const int c  = (ks << 2) + kq;
            s16x8 af[4], bfr[4];
#pragma unroll
            for (int mt = 0; mt < 4; ++mt) {
                int m = wm * 64 + mt * 16 + rr;
                af[mt] = *(const s16x8*)&Ash[(m << 6) + ((c ^ (m & 7)) << 3)];
            }
#pragma unroll
            for (int nt = 0; nt < 4; ++nt) {
                int n = wn * 64 + nt * 16 + rr;
                bfr[nt] = *(const s16x8*)&Bsh[(n << 6) + ((c ^ (n & 7)) << 3)];
            }
#pragma unroll
            for (int mt = 0; mt < 4; ++mt)
#pragma unroll
                for (int nt = 0; nt < 4; ++nt)
                    acc[mt][nt] = __builtin_amdgcn_mfma_f32_16x16x32_bf16(
                        af[mt], bfr[nt], acc[mt][nt], 0, 0, 0);
        }
        __syncthreads();
    }

    // ---- epilogue: C/D layout col=lane&15, row=(lane>>4)*4+reg (measured m89/m91) ----
    const int rr = lane & 15;
    const int rq = lane >> 4;
#pragma unroll
    for (int mt = 0; mt < 4; ++mt)
#pragma unroll
        for (int nt = 0; nt < 4; ++nt)
#pragma unroll
            for (int v = 0; v < 4; ++v) {
                int row = mtile * 128 + wm * 64 + mt * 16 + rq * 4 + v;
                int col = ntile * 128 + wn * 64 + nt * 16 + rr;
                out[(size_t)row * OUT_F + col] = acc[mt][nt][v];
            }
}

// ---------------- host ----------------
extern "C" void kernel_launch(void* const* d_in, const int* in_sizes, int n_in,
                              void* d_out, int out_size, void* d_ws, size_t ws_size,
                              hipStream_t stream) {
    (void)in_sizes; (void)n_in; (void)out_size; (void)ws_size;
    const float* x  = (const float*)d_in[0];   // [16384,256]
    const float* bw = (const float*)d_in[1];   // [256,256]
    const float* sw = (const float*)d_in[2];   // [256,256,31]
    const float* sc = (const float*)d_in[3];   // [256,256]
    float* out = (float*)d_out;

    char* ws = (char*)d_ws;
    unsigned short* Wb = (unsigned short*)ws;                 // 8448*256*2 = 4,325,376 B
    float* pmin = (float*)(ws + 4325376);                     // 131,072
    float* pmax = pmin + 128 * IN_F;                          // 131,072
    float* xmin = pmax + 128 * IN_F;                          // 1,024
    float* rden = xmin + IN_F;                                // 1,024

    minmax_partial<<<128, 256, 0, stream>>>(x, pmin, pmax);
    minmax_final<<<1, 256, 0, stream>>>(pmin, pmax, xmin, rden);
    build_wb<<<256, 256, 0, stream>>>(bw, sw, sc, Wb);
    gemm_kan<<<dim3(128, 2), 256, 0, stream>>>(x, Wb, xmin, rden, out);
}

// Round 11
// 201.411 us; speedup vs baseline: 1.4126x; 1.3856x over previous
//
#include <hip/hip_runtime.h>
#include <stdint.h>

typedef short s16x8 __attribute__((ext_vector_type(8)));
typedef float f32x4 __attribute__((ext_vector_type(4)));

#define IN_F   256
#define OUT_F  256
#define BATCH  16384
#define NB     31
#define KONE   8192
#define KTOT   8448

typedef const __attribute__((address_space(1))) void* as1cvp;
typedef __attribute__((address_space(3))) void* as3vp;

__device__ __forceinline__ unsigned short f2bf(float f) {
    unsigned u = __float_as_uint(f);
    u += 0x7FFFu + ((u >> 16) & 1u);   // RNE
    return (unsigned short)(u >> 16);
}
// monotone f32<->uint key for atomic min/max
__device__ __forceinline__ unsigned fkey(float f) {
    unsigned b = __float_as_uint(f);
    return (b & 0x80000000u) ? ~b : (b | 0x80000000u);
}
__device__ __forceinline__ float funkey(unsigned k) {
    return __uint_as_float((k & 0x80000000u) ? (k & 0x7FFFFFFFu) : ~k);
}

// ---------------- kernel 1: column min/max via punned atomics ----------------
__global__ void minmax_atomic(const float* __restrict__ x,
                              unsigned* __restrict__ pminP, unsigned* __restrict__ pmaxP) {
    const int t = threadIdx.x;
    const int b0 = blockIdx.x * 128;
    float mn = 3.4e38f, mx = -3.4e38f;
    for (int r = 0; r < 128; ++r) {
        float v = x[(size_t)(b0 + r) * IN_F + t];
        mn = fminf(mn, v);
        mx = fmaxf(mx, v);
    }
    atomicMin(&pminP[t], fkey(mn));
    atomicMax(&pmaxP[t], fkey(mx));
}

// ---------------- kernel 2: build W = [Haar-synthesized V | bw] in bf16 ----------------
__global__ void build_wb(const float* __restrict__ bw, const float* __restrict__ sw,
                         const float* __restrict__ sc, unsigned short* __restrict__ Wb) {
    const int o = blockIdx.x;
    const int t = threadIdx.x;
    for (int k = t; k < KTOT; k += 256) {
        float val;
        if (k < KONE) {
            int i = k >> 5, j = k & 31;
            float s = sc[o * IN_F + i];
            float acc = 0.f;
#pragma unroll
            for (int l = 0; l < 5; ++l) {
                int kk = (1 << l) - 1 + (j >> (5 - l));
                float w = sw[((size_t)(o * IN_F + i)) * NB + kk];
                acc += (((j >> (4 - l)) & 1) ? -w : w);
            }
            val = acc * s;
        } else {
            val = bw[o * IN_F + (k - KONE)];
        }
        Wb[(size_t)o * KTOT + k] = f2bf(val);
    }
}

// ---------------- kernel 3: leaf indices, transposed leaf_t[i][b] ----------------
// Verified chain (R9/R10 PASS): xn = (x - xmin) * fl32(1/((xmax-xmin)+1e-8f)),
// leaf = (int)(xn*32.0f); xn>=1.0 -> zero bases (255).
__global__ __launch_bounds__(256) void leafk_t(
    const float* __restrict__ x, const unsigned* __restrict__ pminP,
    const unsigned* __restrict__ pmaxP, unsigned char* __restrict__ lt) {
    __shared__ unsigned char lsh[256 * 128];   // [i][r], 32KB
    __shared__ float xminsh[IN_F], rdensh[IN_F];
    const int t = threadIdx.x;
    const int b0 = blockIdx.x * 128;
    {
        float mn = funkey(pminP[t]), mx = funkey(pmaxP[t]);
        xminsh[t] = mn;
        rdensh[t] = 1.0f / (mx - mn + 1e-8f);
    }
    __syncthreads();
    const float xmn = xminsh[t], rdn = rdensh[t];
    for (int r = 0; r < 128; ++r) {
        float v = x[(size_t)(b0 + r) * IN_F + t];
        float xn = (v - xmn) * rdn;              // rcp-mult (verified)
        int l = (int)(xn * 32.0f);
        lsh[t * 128 + r] = (l >= 0 && l < 32) ? (unsigned char)l : (unsigned char)255;
    }
    __syncthreads();
    // coalesced transposed write: each wave writes 2 rows of 128B per step
    const int lane = t & 63, w = t >> 6;
    const unsigned* lshU = (const unsigned*)lsh;
#pragma unroll
    for (int ib = 0; ib < 32; ++ib) {
        int i = ib * 8 + w * 2 + (lane >> 5);
        unsigned val = lshU[i * 32 + (lane & 31)];
        *(unsigned*)(lt + (size_t)i * BATCH + b0 + (lane & 31) * 4) = val;
    }
}

// ---------------- kernel 4: fused one-hot GEMM, 64x64 tile, single-wave blocks ----
// grid (256, 4) = 1024 blocks -> 4 blocks/CU. Double-buffered B via glds issued
// DURING the MFMA phase (post-MFMA barrier finds loads already landed).
__global__ __launch_bounds__(64, 4) void gemm_kan(
    const float* __restrict__ x,
    const unsigned short* __restrict__ Wb,
    const unsigned char* __restrict__ lt,
    float* __restrict__ out)
{
    __shared__ unsigned short Ash[64 * 64];        // 8KB, XOR-swizzled chunks
    __shared__ unsigned short Bsh[2 * 64 * 64];    // 16KB double buffer

    const int lane  = threadIdx.x;
    const int mtile = blockIdx.x;
    const int ntile = blockIdx.y;

    // zero A tile once; one-hot writes keep it clean
    {
        uint4 z; z.x = z.y = z.z = z.w = 0u;
        uint4* a4 = (uint4*)Ash;
#pragma unroll
        for (int r = 0; r < 8; ++r) a4[lane + r * 64] = z;
    }

    // B glds source base (swizzle: n&7 == lane>>3, q-independent)
    const unsigned char* bbase = (const unsigned char*)(Wb
        + (size_t)(ntile * 64 + (lane >> 3)) * KTOT
        + (((lane & 7) ^ (lane >> 3)) << 3));

    // one-hot identities
    const int am0 = lane >> 1, am1 = 32 + (lane >> 1), ag = lane & 1;
    const size_t lrow0 = (size_t)mtile * 64;
    int ps0 = -1, ps1 = -1;

    unsigned char lf0 = lt[(size_t)ag * BATCH + lrow0 + am0];
    unsigned char lf1 = lt[(size_t)ag * BATCH + lrow0 + am1];

    // issue B(0) into buf0
#pragma unroll
    for (int q = 0; q < 8; ++q)
        __builtin_amdgcn_global_load_lds(
            (as1cvp)(bbase + (size_t)q * 8 * KTOT * 2),
            (as3vp)(uint32_t)(uintptr_t)(Bsh + q * 512), 16, 0, 0);
    __syncthreads();   // drains B(0) + Ash zeros

    f32x4 acc[4][4] = {};
    const int rr = lane & 15, kq = lane >> 4;

    for (int kb = 0; kb < 132; ++kb) {
        const int cur = kb & 1;
        // ---- A phase ----
        if (kb < 128) {
            if (ps0 >= 0) Ash[ps0] = 0;
            if (ps1 >= 0) Ash[ps1] = 0;
            int l0 = lf0, l1 = lf1;
            if (l0 < 32) {
                int c = (ag << 2) + (l0 >> 3);
                ps0 = (am0 << 6) + ((c ^ (am0 & 7)) << 3) + (l0 & 7);
                Ash[ps0] = 0x3F80;
            } else ps0 = -1;
            if (l1 < 32) {
                int c = (ag << 2) + (l1 >> 3);
                ps1 = (am1 << 6) + ((c ^ (am1 & 7)) << 3) + (l1 & 7);
                Ash[ps1] = 0x3F80;
            } else ps1 = -1;
        } else {
            // dense relu(x) tail: full Ash overwrite, coalesced-across-lanes reads
            const float* xr = x + (size_t)(mtile * 64) * IN_F + (kb - 128) * 64 + lane;
            const int cslot = ((lane >> 3));
#pragma unroll
            for (int m = 0; m < 64; ++m) {
                float v = xr[(size_t)m * IN_F];
                Ash[(m << 6) + ((cslot ^ (m & 7)) << 3) + (lane & 7)] = f2bf(fmaxf(v, 0.0f));
            }
        }
        __syncthreads();   // B1: A(kb) visible; nothing big outstanding -> cheap

        // ---- issue B(kb+1) into alt buffer (overlaps MFMA below) ----
        if (kb + 1 < 132) {
            const unsigned char* src = bbase + (size_t)(kb + 1) * 128;
            unsigned short* dst = Bsh + (1 - cur) * 4096;
#pragma unroll
            for (int q = 0; q < 8; ++q)
                __builtin_amdgcn_global_load_lds(
                    (as1cvp)(src + (size_t)q * 8 * KTOT * 2),
                    (as3vp)(uint32_t)(uintptr_t)(dst + q * 512), 16, 0, 0);
        }
        // prefetch leaf bytes for kb+1 (land during MFMA)
        if (kb + 1 < 128) {
            size_t lo = (size_t)((kb + 1) * 2 + ag) * BATCH + lrow0;
            lf0 = lt[lo + am0];
            lf1 = lt[lo + am1];
        }

        // ---- MFMA phase on buf[cur] ----
        const unsigned short* bb = Bsh + cur * 4096;
#pragma unroll
        for (int ks = 0; ks < 2; ++ks) {
            const int c = (ks << 2) + kq;
            s16x8 af[4], bfr[4];
#pragma unroll
            for (int mt = 0; mt < 4; ++mt) {
                int m = mt * 16 + rr;
                af[mt] = *(const s16x8*)&Ash[(m << 6) + ((c ^ (m & 7)) << 3)];
            }
#pragma unroll
            for (int nt = 0; nt < 4; ++nt) {
                int n = nt * 16 + rr;
                bfr[nt] = *(const s16x8*)&bb[(n << 6) + ((c ^ (n & 7)) << 3)];
            }
#pragma unroll
            for (int mt = 0; mt < 4; ++mt)
#pragma unroll
                for (int nt = 0; nt < 4; ++nt)
                    acc[mt][nt] = __builtin_amdgcn_mfma_f32_16x16x32_bf16(
                        af[mt], bfr[nt], acc[mt][nt], 0, 0, 0);
        }
        __syncthreads();   // B2: drains B(kb+1) glds (landed during MFMA) -> cheap
    }

    // ---- epilogue: C/D layout col=lane&15, row=(lane>>4)*4+reg (m89/m91) ----
    const int rq = lane >> 4;
#pragma unroll
    for (int mt = 0; mt < 4; ++mt)
#pragma unroll
        for (int nt = 0; nt < 4; ++nt)
#pragma unroll
            for (int v = 0; v < 4; ++v) {
                int row = mtile * 64 + mt * 16 + rq * 4 + v;
                int col = ntile * 64 + nt * 16 + rr;
                out[(size_t)row * OUT_F + col] = acc[mt][nt][v];
            }
}

// ---------------- host ----------------
extern "C" void kernel_launch(void* const* d_in, const int* in_sizes, int n_in,
                              void* d_out, int out_size, void* d_ws, size_t ws_size,
                              hipStream_t stream) {
    (void)in_sizes; (void)n_in; (void)out_size; (void)ws_size;
    const float* x  = (const float*)d_in[0];   // [16384,256]
    const float* bw = (const float*)d_in[1];   // [256,256]
    const float* sw = (const float*)d_in[2];   // [256,256,31]
    const float* sc = (const float*)d_in[3];   // [256,256]
    float* out = (float*)d_out;

    char* ws = (char*)d_ws;
    unsigned short* Wb   = (unsigned short*)ws;                 // 4,325,376
    unsigned char*  lt   = (unsigned char*)(ws + 4325376);      // 4,194,304
    unsigned*       pminP = (unsigned*)(ws + 8519680);          // 1,024
    unsigned*       pmaxP = (unsigned*)(ws + 8520704);          // 1,024

    hipMemsetAsync(pminP, 0xFF, 1024, stream);   // key-max (identity for atomicMin)
    hipMemsetAsync(pmaxP, 0x00, 1024, stream);   // key-min (identity for atomicMax)

    minmax_atomic<<<128, 256, 0, stream>>>(x, pminP, pmaxP);
    build_wb<<<256, 256, 0, stream>>>(bw, sw, sc, Wb);
    leafk_t<<<128, 256, 0, stream>>>(x, pminP, pmaxP, lt);
    gemm_kan<<<dim3(256, 4), 64, 0, stream>>>(x, Wb, lt, out);
}